// Round 5
// baseline (337.906 us; speedup 1.0000x reference)
//
#include <hip/hip_runtime.h>

#define SEQ  2048
#define DIM  1024
#define HD   64
#define CHUNK_TILES 4
#define MAXCH 8
#define NBLK 512
#define NTHR 256

typedef float f32x4  __attribute__((ext_vector_type(4)));
typedef short bf16x8 __attribute__((ext_vector_type(8)));

__device__ __forceinline__ short f2bf(float x) {          // RNE
    union { float f; unsigned u; } v; v.f = x;
    unsigned r = v.u + 0x7FFFu + ((v.u >> 16) & 1u);
    return (short)(r >> 16);
}
__device__ __forceinline__ short f2bf_fast(float x) {     // round-half-up
    union { float f; unsigned u; } v; v.f = x;
    return (short)((v.u + 0x8000u) >> 16);
}

#define MFMA16(a, b, c) __builtin_amdgcn_mfma_f32_16x16x32_bf16((a), (b), (c), 0, 0, 0)

// Device-scope grid barrier.  All NBLK blocks are co-resident (512 blocks,
// 2/CU guaranteed by __launch_bounds__(256,2) + <=80KB LDS).  Counters are
// zeroed by hipMemsetAsync before each launch (graph-capturable).
__device__ __forceinline__ void gbar(unsigned* cnt, int s) {
    __syncthreads();
    if (threadIdx.x == 0) {
        __threadfence();                               // release: flush writes
        atomicAdd(&cnt[s], 1u);                        // device-scope
        while (__hip_atomic_load(&cnt[s], __ATOMIC_ACQUIRE,
                                 __HIP_MEMORY_SCOPE_AGENT) < (unsigned)NBLK)
            __builtin_amdgcn_s_sleep(2);
        __threadfence();                               // acquire: invalidate
    }
    __syncthreads();
}

__global__ __launch_bounds__(NTHR, 2) void fused_attn_kernel(
    const float* __restrict__ x,
    const float* __restrict__ Wq, const float* __restrict__ bq,
    const float* __restrict__ Wk, const float* __restrict__ bk,
    const float* __restrict__ Wv, const float* __restrict__ bv,
    float* __restrict__ out,
    short* __restrict__ Qs, short* __restrict__ Kb, short* __restrict__ Vt,
    short* __restrict__ wfrag, float* __restrict__ Opart,
    float2* __restrict__ mlpart, unsigned* __restrict__ bar)
{
    // 49152 B reduction area (phase B) / P scratch (phase C) + 3072 B V-bounce
    __shared__ __align__(16) char smem[52224];

    const int tid  = threadIdx.x;
    const int lane = tid & 63;
    const int w    = tid >> 6;          // wave 0..3
    const int c    = lane & 15;
    const int g    = lane >> 4;

    // ================= Phase A: weight repack =================
    {
        const int idx = blockIdx.x * NTHR + tid;       // 0..131071
        if (idx < 24576) {
            const int l  = idx & 63;
            const int n  = (idx >> 6) & 3;
            const int ks = (idx >> 8) & 31;
            const int wv = idx >> 13;
            const float* __restrict__ W = (wv == 0) ? Wq : (wv == 1) ? Wk : Wv;
            bf16x8 v;
#pragma unroll
            for (int j = 0; j < 8; ++j)
                v[j] = f2bf(W[(size_t)(ks * 32 + (l >> 4) * 8 + j) * HD + n * 16 + (l & 15)]);
            *reinterpret_cast<bf16x8*>(wfrag + (size_t)idx * 8) = v;
        }
    }
    gbar(bar, 0);

    // ================= Phase B: QKV projection =================
    // block = one 16-row tile; waves split K 4-ways (8 ks-iters each);
    // LDS f32x4 reduction; wave 0->Q (x0.125), 1->K, 2->Vt (transposed).
    {
        const int r0 = blockIdx.x * 16;
        f32x4 acc[3][4] = {};
        for (int ks = w * 8; ks < w * 8 + 8; ++ks) {
            const float* xp = x + (size_t)(r0 + c) * DIM + ks * 32 + g * 8;
            float4 a0 = *reinterpret_cast<const float4*>(xp);
            float4 a1 = *reinterpret_cast<const float4*>(xp + 4);
            float av[8] = {a0.x, a0.y, a0.z, a0.w, a1.x, a1.y, a1.z, a1.w};
            bf16x8 af;
#pragma unroll
            for (int j = 0; j < 8; ++j) af[j] = f2bf_fast(av[j]);
#pragma unroll
            for (int which = 0; which < 3; ++which)
#pragma unroll
                for (int n = 0; n < 4; ++n) {
                    bf16x8 bfr = *reinterpret_cast<const bf16x8*>(
                        wfrag + ((size_t)((which * 32 + ks) * 4 + n) * 64 + lane) * 8);
                    acc[which][n] = MFMA16(af, bfr, acc[which][n]);
                }
        }
        f32x4* red = (f32x4*)smem;   // [chunk 12][wave 4][lane 64]
#pragma unroll
        for (int which = 0; which < 3; ++which)
#pragma unroll
            for (int n = 0; n < 4; ++n)
                red[((which * 4 + n) * 4 + w) * 64 + lane] = acc[which][n];
        __syncthreads();
        if (w < 3) {
            const float* __restrict__ bias = (w == 0) ? bq : (w == 1) ? bk : bv;
            f32x4 sum[4];
#pragma unroll
            for (int n = 0; n < 4; ++n) {
                sum[n] = red[((w * 4 + n) * 4 + 0) * 64 + lane];
#pragma unroll
                for (int s = 1; s < 4; ++s)
                    sum[n] += red[((w * 4 + n) * 4 + s) * 64 + lane];
            }
            if (w < 2) {
                short* __restrict__ o = (w == 0) ? Qs : Kb;
                const float sc = (w == 0) ? 0.125f : 1.0f;
#pragma unroll
                for (int n = 0; n < 4; ++n) {
                    const float bb = bias[n * 16 + c];
#pragma unroll
                    for (int i = 0; i < 4; ++i)
                        o[(size_t)(r0 + g * 4 + i) * HD + n * 16 + c] =
                            f2bf((sum[n][i] + bb) * sc);
                }
            } else {
                short* ts = (short*)(smem + 49152);    // [16][72]
#pragma unroll
                for (int n = 0; n < 4; ++n) {
                    const float bb = bias[n * 16 + c];
#pragma unroll
                    for (int i = 0; i < 4; ++i)
                        ts[(g * 4 + i) * 72 + n * 16 + c] = f2bf(sum[n][i] + bb);
                }
                // same-wave LDS RAW (compiler inserts lgkmcnt)
                bf16x8 o0, o1;
#pragma unroll
                for (int e = 0; e < 8; ++e) o0[e] = ts[e * 72 + lane];
#pragma unroll
                for (int e = 0; e < 8; ++e) o1[e] = ts[(8 + e) * 72 + lane];
                const int b  = r0 >> 11;
                const int sb = r0 & (SEQ - 1);
                short* dst = Vt + (((size_t)(b * 64 + lane)) << 11) + sb;
                *reinterpret_cast<bf16x8*>(dst)     = o0;
                *reinterpret_cast<bf16x8*>(dst + 8) = o1;
            }
        }
    }
    gbar(bar, 1);

    // ================= Phase C: split-key attention partials =================
    {
        const int wid = blockIdx.x * 4 + w;            // 0..2047
        short* P = (short*)(smem + (size_t)w * 8448);  // per-wave [16][264]
        for (int u = wid; u < 4096; u += 2048) {
            const int qb    = u >> 3;
            const int cid   = u & 7;
            const int q0g   = qb * 16;
            const int b     = q0g >> 11;
            const int qbase = q0g & (SEQ - 1);
            const int tlast = qbase >> 6;
            const int t0    = cid * CHUNK_TILES;
            if (t0 > tlast) continue;
            const int nact = min(CHUNK_TILES, tlast - t0 + 1);

            bf16x8 qf[2];
            qf[0] = *reinterpret_cast<const bf16x8*>(Qs + (size_t)(q0g + c) * HD + g * 8);
            qf[1] = *reinterpret_cast<const bf16x8*>(Qs + (size_t)(q0g + c) * HD + 32 + g * 8);

            const size_t krow0 = (size_t)b * SEQ;

            f32x4 S[CHUNK_TILES][4] = {};
#pragma unroll
            for (int tt = 0; tt < CHUNK_TILES; ++tt) {
                if (tt >= nact) continue;
                const int key0 = (t0 + tt) * 64;
                bf16x8 kf[4][2];
#pragma unroll
                for (int n = 0; n < 4; ++n)
#pragma unroll
                    for (int st = 0; st < 2; ++st)
                        kf[n][st] = *reinterpret_cast<const bf16x8*>(
                            Kb + (krow0 + key0 + n * 16 + c) * HD + st * 32 + g * 8);
#pragma unroll
                for (int st = 0; st < 2; ++st)
#pragma unroll
                    for (int n = 0; n < 4; ++n)
                        S[tt][n] = MFMA16(qf[st], kf[n][st], S[tt][n]);
            }

            if (tlast - t0 < CHUNK_TILES) {
                const int ttd  = tlast - t0;
                const int key0 = tlast * 64;
#pragma unroll
                for (int tt = 0; tt < CHUNK_TILES; ++tt) {
                    if (tt != ttd) continue;
#pragma unroll
                    for (int n = 0; n < 4; ++n)
#pragma unroll
                        for (int i = 0; i < 4; ++i)
                            if (key0 + n * 16 + c > qbase + g * 4 + i)
                                S[tt][n][i] = -__builtin_inff();
                }
            }

            float mx[4], rs[4];
#pragma unroll
            for (int i = 0; i < 4; ++i) { mx[i] = -__builtin_inff(); rs[i] = 0.f; }
#pragma unroll
            for (int tt = 0; tt < CHUNK_TILES; ++tt) {
                if (tt >= nact) continue;
#pragma unroll
                for (int n = 0; n < 4; ++n)
#pragma unroll
                    for (int i = 0; i < 4; ++i)
                        mx[i] = fmaxf(mx[i], S[tt][n][i]);
            }
#pragma unroll
            for (int off = 1; off <= 8; off <<= 1)
#pragma unroll
                for (int i = 0; i < 4; ++i)
                    mx[i] = fmaxf(mx[i], __shfl_xor(mx[i], off, 64));
#pragma unroll
            for (int tt = 0; tt < CHUNK_TILES; ++tt) {
                if (tt >= nact) continue;
#pragma unroll
                for (int n = 0; n < 4; ++n)
#pragma unroll
                    for (int i = 0; i < 4; ++i) {
                        const float p = __expf(S[tt][n][i] - mx[i]);
                        S[tt][n][i] = p;
                        rs[i] += p;
                    }
            }
#pragma unroll
            for (int off = 1; off <= 8; off <<= 1)
#pragma unroll
                for (int i = 0; i < 4; ++i)
                    rs[i] += __shfl_xor(rs[i], off, 64);

#pragma unroll
            for (int tt = 0; tt < CHUNK_TILES; ++tt) {
                if (tt >= nact) continue;
#pragma unroll
                for (int n = 0; n < 4; ++n)
#pragma unroll
                    for (int i = 0; i < 4; ++i)
                        P[(g * 4 + i) * 264 + tt * 64 + n * 16 + c] = f2bf_fast(S[tt][n][i]);
            }

            f32x4 O[4] = {};
#pragma unroll
            for (int tt = 0; tt < CHUNK_TILES; ++tt) {
                if (tt >= nact) continue;
                const int key0 = (t0 + tt) * 64;
#pragma unroll
                for (int st = 0; st < 2; ++st) {
                    bf16x8 pf = *reinterpret_cast<const bf16x8*>(
                        &P[c * 264 + tt * 64 + st * 32 + g * 8]);
#pragma unroll
                    for (int n = 0; n < 4; ++n) {
                        bf16x8 vf = *reinterpret_cast<const bf16x8*>(
                            Vt + (((size_t)(b * 64 + n * 16 + c)) << 11) + key0 + st * 32 + g * 8);
                        O[n] = MFMA16(pf, vf, O[n]);
                    }
                }
            }

            float* op = Opart + ((size_t)(qb * MAXCH + cid) * 16) * 64;
#pragma unroll
            for (int n = 0; n < 4; ++n)
#pragma unroll
                for (int i = 0; i < 4; ++i)
                    op[(size_t)(g * 4 + i) * 64 + n * 16 + c] = O[n][i];
            if (c == 0) {
#pragma unroll
                for (int i = 0; i < 4; ++i)
                    mlpart[(size_t)(qb * MAXCH + cid) * 16 + g * 4 + i] =
                        make_float2(mx[i], rs[i]);
            }
        }
    }
    gbar(bar, 2);

    // ================= Phase D: combine =================
    {
        const int wid = blockIdx.x * 4 + w;   // 0..2047
        const int qb  = wid >> 2;
        const int rg  = wid & 3;
        const int d   = lane;
        const int qbase = (qb * 16) & (SEQ - 1);
        const int NC = (qbase >> 6) / CHUNK_TILES + 1;

#pragma unroll
        for (int ri = 0; ri < 4; ++ri) {
            const int r = rg * 4 + ri;
            float m = -__builtin_inff();
            for (int ci = 0; ci < NC; ++ci)
                m = fmaxf(m, mlpart[(size_t)(qb * MAXCH + ci) * 16 + r].x);
            float l = 0.f, o = 0.f;
            for (int ci = 0; ci < NC; ++ci) {
                const float2 ml = mlpart[(size_t)(qb * MAXCH + ci) * 16 + r];
                const float wgt = __expf(ml.x - m);
                l += wgt * ml.y;
                o += wgt * Opart[((size_t)(qb * MAXCH + ci) * 16 + r) * 64 + d];
            }
            out[(size_t)(qb * 16 + r) * HD + d] = o / l;
        }
    }
}

// ---------------------------------------------------------------------------
extern "C" void kernel_launch(void* const* d_in, const int* in_sizes, int n_in,
                              void* d_out, int out_size, void* d_ws, size_t ws_size,
                              hipStream_t stream)
{
    (void)in_sizes; (void)n_in; (void)out_size;
    const float* x  = (const float*)d_in[0];
    const float* Wq = (const float*)d_in[1];
    const float* bq = (const float*)d_in[2];
    const float* Wk = (const float*)d_in[3];
    const float* bk = (const float*)d_in[4];
    const float* Wv = (const float*)d_in[5];
    const float* bv = (const float*)d_in[6];
    float* out = (float*)d_out;

    char* ws = (char*)d_ws;
    short*    Qs     = (short*)(ws);                  // 1 MB
    short*    Kb     = (short*)(ws + (1u << 20));     // 1 MB
    short*    Vt     = (short*)(ws + (2u << 20));     // 1 MB  [4][64][2048]
    short*    wfrag  = (short*)(ws + (3u << 20));     // 384 KB
    float*    Opart  = (float*)(ws + (4u << 20));     // 16 MB
    float2*   mlpart = (float2*)(ws + (20u << 20));   // 512 KB
    unsigned* bar    = (unsigned*)(ws + (21u << 20)); // 64 B
    const size_t needed = (21u << 20) + 64;
    if (ws_size < needed) return;   // cannot happen (R3/R4 ran split path)

    hipMemsetAsync(bar, 0, 64, stream);
    fused_attn_kernel<<<NBLK, NTHR, 0, stream>>>(
        x, Wq, bq, Wk, bk, Wv, bv, out, Qs, Kb, Vt, wfrag, Opart, mlpart, bar);
}

// Round 6
// 214.577 us; speedup vs baseline: 1.5748x; 1.5748x over previous
//
#include <hip/hip_runtime.h>

#define SEQ  2048
#define DIM  1024
#define HD   64
#define CT   4                 // key tiles per chunk (256 keys)
#define MAXCH 8

typedef float f32x4  __attribute__((ext_vector_type(4)));
typedef short bf16x8 __attribute__((ext_vector_type(8)));

__device__ __forceinline__ short f2bf(float x) {          // RNE
    union { float f; unsigned u; } v; v.f = x;
    unsigned r = v.u + 0x7FFFu + ((v.u >> 16) & 1u);
    return (short)(r >> 16);
}
__device__ __forceinline__ short f2bf_fast(float x) {     // round-half-up
    union { float f; unsigned u; } v; v.f = x;
    return (short)((v.u + 0x8000u) >> 16);
}

#define MFMA16(a, b, c) __builtin_amdgcn_mfma_f32_16x16x32_bf16((a), (b), (c), 0, 0, 0)

// ---------------------------------------------------------------------------
// wprep: repack Wq/Wk/Wv (fp32 [1024][64]) into bf16 MFMA B-fragment order:
// wfrag[which][kstep 32][nfrag 4][lane 64][8].
// ---------------------------------------------------------------------------
__global__ __launch_bounds__(256) void wprep_kernel(
    const float* __restrict__ Wq, const float* __restrict__ Wk,
    const float* __restrict__ Wv, short* __restrict__ wfrag)
{
    const int idx = blockIdx.x * 256 + threadIdx.x;   // 0..24575
    const int l  = idx & 63;
    const int n  = (idx >> 6) & 3;
    const int ks = (idx >> 8) & 31;
    const int w  = idx >> 13;
    const float* __restrict__ W = (w == 0) ? Wq : (w == 1) ? Wk : Wv;
    bf16x8 v;
#pragma unroll
    for (int j = 0; j < 8; ++j)
        v[j] = f2bf(W[(size_t)(ks * 32 + (l >> 4) * 8 + j) * HD + n * 16 + (l & 15)]);
    *reinterpret_cast<bf16x8*>(wfrag + (size_t)idx * 8) = v;
}

// ---------------------------------------------------------------------------
// proj: grid (128, 3), block 256 (4 waves).  Wave w computes the 16-row tile
// (blockIdx.x*4 + w) of output `which` = blockIdx.y.  Q pre-scaled by 0.125.
// V written transposed to Vt via per-wave LDS bounce (no barrier needed).
// ---------------------------------------------------------------------------
__global__ __launch_bounds__(256) void proj_kernel(
    const float* __restrict__ x, const short* __restrict__ wfrag,
    const float* __restrict__ bq, const float* __restrict__ bk,
    const float* __restrict__ bv,
    short* __restrict__ Qs, short* __restrict__ Kb, short* __restrict__ Vt)
{
    __shared__ short ts[4][16 * 72];

    const int tid  = threadIdx.x;
    const int lane = tid & 63;
    const int w    = tid >> 6;
    const int c    = lane & 15;
    const int g    = lane >> 4;
    const int r0   = (blockIdx.x * 4 + w) * 16;
    const int which = blockIdx.y;

    const float* __restrict__ bias = (which == 0) ? bq : (which == 1) ? bk : bv;
    const short* __restrict__ wf = wfrag + (size_t)which * 32 * 4 * 64 * 8;

    f32x4 acc[4] = {};

    for (int ks = 0; ks < 32; ++ks) {
        const float* xp = x + (size_t)(r0 + c) * DIM + ks * 32 + g * 8;
        float4 a0 = *reinterpret_cast<const float4*>(xp);
        float4 a1 = *reinterpret_cast<const float4*>(xp + 4);
        float av[8] = {a0.x, a0.y, a0.z, a0.w, a1.x, a1.y, a1.z, a1.w};
        bf16x8 af;
#pragma unroll
        for (int j = 0; j < 8; ++j) af[j] = f2bf_fast(av[j]);
#pragma unroll
        for (int n = 0; n < 4; ++n) {
            bf16x8 bfr = *reinterpret_cast<const bf16x8*>(
                wf + ((size_t)(ks * 4 + n) * 64 + lane) * 8);
            acc[n] = MFMA16(af, bfr, acc[n]);
        }
    }

    if (which < 2) {
        short* __restrict__ o = (which == 0) ? Qs : Kb;
        const float sc = (which == 0) ? 0.125f : 1.0f;
#pragma unroll
        for (int n = 0; n < 4; ++n) {
            const float bb = bias[n * 16 + c];
#pragma unroll
            for (int i = 0; i < 4; ++i)
                o[(size_t)(r0 + g * 4 + i) * HD + n * 16 + c] =
                    f2bf((acc[n][i] + bb) * sc);
        }
    } else {
        short* t = ts[w];
#pragma unroll
        for (int n = 0; n < 4; ++n) {
            const float bb = bias[n * 16 + c];
#pragma unroll
            for (int i = 0; i < 4; ++i)
                t[(g * 4 + i) * 72 + n * 16 + c] = f2bf(acc[n][i] + bb);
        }
        // same-wave LDS RAW: compiler inserts lgkmcnt wait
        bf16x8 o0, o1;
#pragma unroll
        for (int e = 0; e < 8; ++e) o0[e] = t[e * 72 + lane];
#pragma unroll
        for (int e = 0; e < 8; ++e) o1[e] = t[(8 + e) * 72 + lane];
        const int b  = r0 >> 11;
        const int sb = r0 & (SEQ - 1);
        short* dst = Vt + (((size_t)(b * 64 + lane)) << 11) + sb;
        *reinterpret_cast<bf16x8*>(dst)     = o0;
        *reinterpret_cast<bf16x8*>(dst + 8) = o1;
    }
}

// ===========================================================================
// attn: split-key partials + fused "last unit combines" reduction.
// Exactly 2304 active units mapped onto 576 blocks x 4 waves (no empties):
//   per batch (576 units): group g (=qloc/16, 0..7) has 16 q-tiles x (g+1)
//   chunks; cumulative offset C(g) = 8g(g+1).
// Unit = (q-tile qb, chunk cid): phase1 QK MFMAs, one exact softmax,
// P->LDS, PV MFMAs, write partials; then atomic counter -- the unit that
// arrives last for qb performs the combine for all 16 rows.
// ===========================================================================
__global__ __launch_bounds__(256) void attn_kernel(
    const short* __restrict__ Qs, const short* __restrict__ Kb,
    const short* __restrict__ Vt, float* __restrict__ Opart,
    float2* __restrict__ mlpart, unsigned* __restrict__ cnt,
    float* __restrict__ out)
{
    __shared__ short P_all[4][16 * 264];

    const int tid  = threadIdx.x;
    const int lane = tid & 63;
    const int w    = tid >> 6;
    const int c    = lane & 15;
    const int g    = lane >> 4;

    const int u     = blockIdx.x * 4 + w;       // 0..2303
    const int batch = u / 576;
    const int up    = u - batch * 576;
    int grp = 0;
#pragma unroll
    for (int t = 1; t < 8; ++t) if (up >= 8 * t * (t + 1)) grp = t;
    const int r    = up - 8 * grp * (grp + 1);
    const int qloc = grp * 16 + (r & 15);
    const int cid  = r >> 4;                    // 0..grp
    const int qb   = batch * 128 + qloc;
    const int q0g  = qb * 16;
    const int qbase = qloc * 16;
    const int tlast = qloc >> 2;
    const int t0    = cid * CT;
    const int nact  = min(CT, tlast - t0 + 1);

    short* P = P_all[w];

    bf16x8 qf[2];
    qf[0] = *reinterpret_cast<const bf16x8*>(Qs + (size_t)(q0g + c) * HD + g * 8);
    qf[1] = *reinterpret_cast<const bf16x8*>(Qs + (size_t)(q0g + c) * HD + 32 + g * 8);

    const size_t krow0 = (size_t)batch * SEQ;

    // ---- Phase 1: QK^T for all active tiles ----
    f32x4 S[CT][4] = {};
#pragma unroll
    for (int tt = 0; tt < CT; ++tt) {
        if (tt >= nact) continue;               // wave-uniform
        const int key0 = (t0 + tt) * 64;
        bf16x8 kf[4][2];
#pragma unroll
        for (int n = 0; n < 4; ++n)
#pragma unroll
            for (int st = 0; st < 2; ++st)
                kf[n][st] = *reinterpret_cast<const bf16x8*>(
                    Kb + (krow0 + key0 + n * 16 + c) * HD + st * 32 + g * 8);
#pragma unroll
        for (int st = 0; st < 2; ++st)
#pragma unroll
            for (int n = 0; n < 4; ++n)
                S[tt][n] = MFMA16(qf[st], kf[n][st], S[tt][n]);
    }

    // causal mask: only diagonal tile
    if (tlast - t0 < CT) {
        const int ttd  = tlast - t0;
        const int key0 = tlast * 64;
#pragma unroll
        for (int tt = 0; tt < CT; ++tt) {
            if (tt != ttd) continue;
#pragma unroll
            for (int n = 0; n < 4; ++n)
#pragma unroll
                for (int i = 0; i < 4; ++i)
                    if (key0 + n * 16 + c > qbase + g * 4 + i)
                        S[tt][n][i] = -__builtin_inff();
        }
    }

    // ---- Phase 2: one exact softmax over the chunk ----
    float mx[4], rs[4];
#pragma unroll
    for (int i = 0; i < 4; ++i) { mx[i] = -__builtin_inff(); rs[i] = 0.f; }
#pragma unroll
    for (int tt = 0; tt < CT; ++tt) {
        if (tt >= nact) continue;
#pragma unroll
        for (int n = 0; n < 4; ++n)
#pragma unroll
            for (int i = 0; i < 4; ++i)
                mx[i] = fmaxf(mx[i], S[tt][n][i]);
    }
#pragma unroll
    for (int off = 1; off <= 8; off <<= 1)
#pragma unroll
        for (int i = 0; i < 4; ++i)
            mx[i] = fmaxf(mx[i], __shfl_xor(mx[i], off, 64));
#pragma unroll
    for (int tt = 0; tt < CT; ++tt) {
        if (tt >= nact) continue;
#pragma unroll
        for (int n = 0; n < 4; ++n)
#pragma unroll
            for (int i = 0; i < 4; ++i) {
                const float p = __expf(S[tt][n][i] - mx[i]);
                S[tt][n][i] = p;
                rs[i] += p;
            }
    }
#pragma unroll
    for (int off = 1; off <= 8; off <<= 1)
#pragma unroll
        for (int i = 0; i < 4; ++i)
            rs[i] += __shfl_xor(rs[i], off, 64);

    // ---- Phase 3: P -> LDS, PV ----
#pragma unroll
    for (int tt = 0; tt < CT; ++tt) {
        if (tt >= nact) continue;
#pragma unroll
        for (int n = 0; n < 4; ++n)
#pragma unroll
            for (int i = 0; i < 4; ++i)
                P[(g * 4 + i) * 264 + tt * 64 + n * 16 + c] = f2bf_fast(S[tt][n][i]);
    }
    // same-wave LDS RAW: compiler inserts lgkmcnt wait

    f32x4 O[4] = {};
#pragma unroll
    for (int tt = 0; tt < CT; ++tt) {
        if (tt >= nact) continue;
        const int key0 = (t0 + tt) * 64;
#pragma unroll
        for (int st = 0; st < 2; ++st) {
            bf16x8 pf = *reinterpret_cast<const bf16x8*>(
                &P[c * 264 + tt * 64 + st * 32 + g * 8]);
#pragma unroll
            for (int n = 0; n < 4; ++n) {
                bf16x8 vf = *reinterpret_cast<const bf16x8*>(
                    Vt + (((size_t)(batch * 64 + n * 16 + c)) << 11) + key0 + st * 32 + g * 8);
                O[n] = MFMA16(pf, vf, O[n]);
            }
        }
    }

    // ---- write partials ----
    float* op = Opart + ((size_t)(qb * MAXCH + cid) * 16) * 64;
#pragma unroll
    for (int n = 0; n < 4; ++n)
#pragma unroll
        for (int i = 0; i < 4; ++i)
            op[(size_t)(g * 4 + i) * 64 + n * 16 + c] = O[n][i];
    if (c == 0) {
#pragma unroll
        for (int i = 0; i < 4; ++i)
            mlpart[(size_t)(qb * MAXCH + cid) * 16 + g * 4 + i] =
                make_float2(mx[i], rs[i]);
    }

    // ---- last unit for this q-tile combines (no spinning: one fence+atomic) ----
    __threadfence();                            // release partial writes
    int old = 0;
    if (lane == 0) old = (int)atomicAdd(&cnt[qb], 1u);
    old = __shfl(old, 0);
    if (old == grp) {                           // grp == NC-1 -> we are last
        __threadfence();                        // acquire others' partials
        const int NC = grp + 1;
        for (int rr = 0; rr < 16; ++rr) {
            float m = -__builtin_inff();
            for (int ci = 0; ci < NC; ++ci)
                m = fmaxf(m, mlpart[(size_t)(qb * MAXCH + ci) * 16 + rr].x);
            float l = 0.f, o = 0.f;
            for (int ci = 0; ci < NC; ++ci) {
                const float2 ml = mlpart[(size_t)(qb * MAXCH + ci) * 16 + rr];
                const float wgt = __expf(ml.x - m);
                l += wgt * ml.y;
                o += wgt * Opart[((size_t)(qb * MAXCH + ci) * 16 + rr) * 64 + lane];
            }
            out[(size_t)(q0g + rr) * HD + lane] = o / l;
        }
    }
}

// ---------------------------------------------------------------------------
extern "C" void kernel_launch(void* const* d_in, const int* in_sizes, int n_in,
                              void* d_out, int out_size, void* d_ws, size_t ws_size,
                              hipStream_t stream)
{
    (void)in_sizes; (void)n_in; (void)out_size; (void)ws_size;
    const float* x  = (const float*)d_in[0];
    const float* Wq = (const float*)d_in[1];
    const float* bq = (const float*)d_in[2];
    const float* Wk = (const float*)d_in[3];
    const float* bk = (const float*)d_in[4];
    const float* Wv = (const float*)d_in[5];
    const float* bv = (const float*)d_in[6];
    float* out = (float*)d_out;

    char* ws = (char*)d_ws;
    short*    Qs     = (short*)(ws);                  // 1 MB
    short*    Kb     = (short*)(ws + (1u << 20));     // 1 MB
    short*    Vt     = (short*)(ws + (2u << 20));     // 1 MB  [4][64][2048]
    short*    wfrag  = (short*)(ws + (3u << 20));     // 384 KB
    float*    Opart  = (float*)(ws + (4u << 20));     // 16 MB
    float2*   mlpart = (float2*)(ws + (20u << 20));   // 512 KB
    unsigned* cnt    = (unsigned*)(ws + (21u << 20)); // 2 KB

    hipMemsetAsync(cnt, 0, 512 * sizeof(unsigned), stream);
    wprep_kernel<<<96, 256, 0, stream>>>(Wq, Wk, Wv, wfrag);
    proj_kernel<<<dim3(128, 3), 256, 0, stream>>>(x, wfrag, bq, bk, bv, Qs, Kb, Vt);
    attn_kernel<<<576, 256, 0, stream>>>(Qs, Kb, Vt, Opart, mlpart, cnt, out);
}

// Round 7
// 71.101 us; speedup vs baseline: 4.7525x; 3.0179x over previous
//
#include <hip/hip_runtime.h>

#define SEQ  2048
#define DIM  1024
#define HD   64
#define CT   4                 // key tiles per chunk (256 keys)
#define MAXCH 8

typedef float f32x4  __attribute__((ext_vector_type(4)));
typedef short bf16x8 __attribute__((ext_vector_type(8)));

__device__ __forceinline__ short f2bf(float x) {          // RNE
    union { float f; unsigned u; } v; v.f = x;
    unsigned r = v.u + 0x7FFFu + ((v.u >> 16) & 1u);
    return (short)(r >> 16);
}
__device__ __forceinline__ short f2bf_fast(float x) {     // round-half-up
    union { float f; unsigned u; } v; v.f = x;
    return (short)((v.u + 0x8000u) >> 16);
}

#define MFMA16(a, b, c) __builtin_amdgcn_mfma_f32_16x16x32_bf16((a), (b), (c), 0, 0, 0)

// ---------------------------------------------------------------------------
// wprep: repack Wq/Wk/Wv (fp32 [1024][64]) into bf16 MFMA B-fragment order:
// wfrag[which][kstep 32][nfrag 4][lane 64][8].
// ---------------------------------------------------------------------------
__global__ __launch_bounds__(256) void wprep_kernel(
    const float* __restrict__ Wq, const float* __restrict__ Wk,
    const float* __restrict__ Wv, short* __restrict__ wfrag)
{
    const int idx = blockIdx.x * 256 + threadIdx.x;   // 0..24575
    const int l  = idx & 63;
    const int n  = (idx >> 6) & 3;
    const int ks = (idx >> 8) & 31;
    const int w  = idx >> 13;
    const float* __restrict__ W = (w == 0) ? Wq : (w == 1) ? Wk : Wv;
    bf16x8 v;
#pragma unroll
    for (int j = 0; j < 8; ++j)
        v[j] = f2bf(W[(size_t)(ks * 32 + (l >> 4) * 8 + j) * HD + n * 16 + (l & 15)]);
    *reinterpret_cast<bf16x8*>(wfrag + (size_t)idx * 8) = v;
}

// ---------------------------------------------------------------------------
// proj: grid 512, block 256 (4 waves).  Block = one 16-row tile of ALL THREE
// outputs; waves split K 4-ways (8 ks-iters each; 1/4 the serial chain);
// f32x4 LDS reduction; wave 0 -> Q (x0.125), 1 -> K, 2 -> Vt (transposed).
// x is read exactly once (32 MB total vs 96 MB in the per-which variant).
// ---------------------------------------------------------------------------
__global__ __launch_bounds__(256) void proj_kernel(
    const float* __restrict__ x, const short* __restrict__ wfrag,
    const float* __restrict__ bq, const float* __restrict__ bk,
    const float* __restrict__ bv,
    short* __restrict__ Qs, short* __restrict__ Kb, short* __restrict__ Vt)
{
    __shared__ __align__(16) char smem[49152 + 2304];

    const int tid  = threadIdx.x;
    const int lane = tid & 63;
    const int w    = tid >> 6;
    const int c    = lane & 15;
    const int g    = lane >> 4;
    const int r0   = blockIdx.x * 16;

    f32x4 acc[3][4] = {};
    for (int ks = w * 8; ks < w * 8 + 8; ++ks) {
        const float* xp = x + (size_t)(r0 + c) * DIM + ks * 32 + g * 8;
        float4 a0 = *reinterpret_cast<const float4*>(xp);
        float4 a1 = *reinterpret_cast<const float4*>(xp + 4);
        float av[8] = {a0.x, a0.y, a0.z, a0.w, a1.x, a1.y, a1.z, a1.w};
        bf16x8 af;
#pragma unroll
        for (int j = 0; j < 8; ++j) af[j] = f2bf_fast(av[j]);
#pragma unroll
        for (int which = 0; which < 3; ++which)
#pragma unroll
            for (int n = 0; n < 4; ++n) {
                bf16x8 bfr = *reinterpret_cast<const bf16x8*>(
                    wfrag + ((size_t)((which * 32 + ks) * 4 + n) * 64 + lane) * 8);
                acc[which][n] = MFMA16(af, bfr, acc[which][n]);
            }
    }

    f32x4* red = (f32x4*)smem;   // [chunk 12][wave 4][lane 64]
#pragma unroll
    for (int which = 0; which < 3; ++which)
#pragma unroll
        for (int n = 0; n < 4; ++n)
            red[((which * 4 + n) * 4 + w) * 64 + lane] = acc[which][n];
    __syncthreads();

    if (w < 3) {
        const float* __restrict__ bias = (w == 0) ? bq : (w == 1) ? bk : bv;
        f32x4 sum[4];
#pragma unroll
        for (int n = 0; n < 4; ++n) {
            sum[n] = red[((w * 4 + n) * 4 + 0) * 64 + lane];
#pragma unroll
            for (int s = 1; s < 4; ++s)
                sum[n] += red[((w * 4 + n) * 4 + s) * 64 + lane];
        }
        if (w < 2) {
            short* __restrict__ o = (w == 0) ? Qs : Kb;
            const float sc = (w == 0) ? 0.125f : 1.0f;
#pragma unroll
            for (int n = 0; n < 4; ++n) {
                const float bb = bias[n * 16 + c];
#pragma unroll
                for (int i = 0; i < 4; ++i)
                    o[(size_t)(r0 + g * 4 + i) * HD + n * 16 + c] =
                        f2bf((sum[n][i] + bb) * sc);
            }
        } else {
            short* ts = (short*)(smem + 49152);    // [16][72]
#pragma unroll
            for (int n = 0; n < 4; ++n) {
                const float bb = bias[n * 16 + c];
#pragma unroll
                for (int i = 0; i < 4; ++i)
                    ts[(g * 4 + i) * 72 + n * 16 + c] = f2bf(sum[n][i] + bb);
            }
            // same-wave LDS RAW: compiler inserts lgkmcnt wait
            bf16x8 o0, o1;
#pragma unroll
            for (int e = 0; e < 8; ++e) o0[e] = ts[e * 72 + lane];
#pragma unroll
            for (int e = 0; e < 8; ++e) o1[e] = ts[(8 + e) * 72 + lane];
            const int b  = r0 >> 11;
            const int sb = r0 & (SEQ - 1);
            short* dst = Vt + (((size_t)(b * 64 + lane)) << 11) + sb;
            *reinterpret_cast<bf16x8*>(dst)     = o0;
            *reinterpret_cast<bf16x8*>(dst + 8) = o1;
        }
    }
}

// ===========================================================================
// attn: split-key partials.  Exactly 2304 active units on 576 blocks x 4
// waves (no empty blocks).  Per batch (576 units): group g (=qloc/16, 0..7)
// has 16 q-tiles x (g+1) chunks; cumulative offset C(g) = 8g(g+1).
// Unit = (q-tile, chunk): QK MFMAs for <=4 key tiles, ONE exact softmax,
// P->LDS, PV MFMAs, write unnormalized partials.  NO fences, NO atomics.
// ===========================================================================
__global__ __launch_bounds__(256) void attn_kernel(
    const short* __restrict__ Qs, const short* __restrict__ Kb,
    const short* __restrict__ Vt, float* __restrict__ Opart,
    float2* __restrict__ mlpart)
{
    __shared__ short P_all[4][16 * 264];

    const int tid  = threadIdx.x;
    const int lane = tid & 63;
    const int w    = tid >> 6;
    const int c    = lane & 15;
    const int g    = lane >> 4;

    const int u     = blockIdx.x * 4 + w;       // 0..2303
    const int batch = u / 576;
    const int up    = u - batch * 576;
    int grp = 0;
#pragma unroll
    for (int t = 1; t < 8; ++t) if (up >= 8 * t * (t + 1)) grp = t;
    const int r    = up - 8 * grp * (grp + 1);
    const int qloc = grp * 16 + (r & 15);
    const int cid  = r >> 4;                    // 0..grp
    const int qb   = batch * 128 + qloc;
    const int q0g  = qb * 16;
    const int qbase = qloc * 16;
    const int tlast = qloc >> 2;
    const int t0    = cid * CT;
    const int nact  = min(CT, tlast - t0 + 1);

    short* P = P_all[w];

    bf16x8 qf[2];
    qf[0] = *reinterpret_cast<const bf16x8*>(Qs + (size_t)(q0g + c) * HD + g * 8);
    qf[1] = *reinterpret_cast<const bf16x8*>(Qs + (size_t)(q0g + c) * HD + 32 + g * 8);

    const size_t krow0 = (size_t)batch * SEQ;

    // ---- Phase 1: QK^T for all active tiles ----
    f32x4 S[CT][4] = {};
#pragma unroll
    for (int tt = 0; tt < CT; ++tt) {
        if (tt >= nact) continue;               // wave-uniform
        const int key0 = (t0 + tt) * 64;
        bf16x8 kf[4][2];
#pragma unroll
        for (int n = 0; n < 4; ++n)
#pragma unroll
            for (int st = 0; st < 2; ++st)
                kf[n][st] = *reinterpret_cast<const bf16x8*>(
                    Kb + (krow0 + key0 + n * 16 + c) * HD + st * 32 + g * 8);
#pragma unroll
        for (int st = 0; st < 2; ++st)
#pragma unroll
            for (int n = 0; n < 4; ++n)
                S[tt][n] = MFMA16(qf[st], kf[n][st], S[tt][n]);
    }

    // causal mask: only diagonal tile
    if (tlast - t0 < CT) {
        const int ttd  = tlast - t0;
        const int key0 = tlast * 64;
#pragma unroll
        for (int tt = 0; tt < CT; ++tt) {
            if (tt != ttd) continue;
#pragma unroll
            for (int n = 0; n < 4; ++n)
#pragma unroll
                for (int i = 0; i < 4; ++i)
                    if (key0 + n * 16 + c > qbase + g * 4 + i)
                        S[tt][n][i] = -__builtin_inff();
        }
    }

    // ---- Phase 2: one exact softmax over the chunk ----
    float mx[4], rs[4];
#pragma unroll
    for (int i = 0; i < 4; ++i) { mx[i] = -__builtin_inff(); rs[i] = 0.f; }
#pragma unroll
    for (int tt = 0; tt < CT; ++tt) {
        if (tt >= nact) continue;
#pragma unroll
        for (int n = 0; n < 4; ++n)
#pragma unroll
            for (int i = 0; i < 4; ++i)
                mx[i] = fmaxf(mx[i], S[tt][n][i]);
    }
#pragma unroll
    for (int off = 1; off <= 8; off <<= 1)
#pragma unroll
        for (int i = 0; i < 4; ++i)
            mx[i] = fmaxf(mx[i], __shfl_xor(mx[i], off, 64));
#pragma unroll
    for (int tt = 0; tt < CT; ++tt) {
        if (tt >= nact) continue;
#pragma unroll
        for (int n = 0; n < 4; ++n)
#pragma unroll
            for (int i = 0; i < 4; ++i) {
                const float p = __expf(S[tt][n][i] - mx[i]);
                S[tt][n][i] = p;
                rs[i] += p;
            }
    }
#pragma unroll
    for (int off = 1; off <= 8; off <<= 1)
#pragma unroll
        for (int i = 0; i < 4; ++i)
            rs[i] += __shfl_xor(rs[i], off, 64);

    // ---- Phase 3: P -> LDS, PV ----
#pragma unroll
    for (int tt = 0; tt < CT; ++tt) {
        if (tt >= nact) continue;
#pragma unroll
        for (int n = 0; n < 4; ++n)
#pragma unroll
            for (int i = 0; i < 4; ++i)
                P[(g * 4 + i) * 264 + tt * 64 + n * 16 + c] = f2bf_fast(S[tt][n][i]);
    }
    // same-wave LDS RAW: compiler inserts lgkmcnt wait

    f32x4 O[4] = {};
#pragma unroll
    for (int tt = 0; tt < CT; ++tt) {
        if (tt >= nact) continue;
        const int key0 = (t0 + tt) * 64;
#pragma unroll
        for (int st = 0; st < 2; ++st) {
            bf16x8 pf = *reinterpret_cast<const bf16x8*>(
                &P[c * 264 + tt * 64 + st * 32 + g * 8]);
#pragma unroll
            for (int n = 0; n < 4; ++n) {
                bf16x8 vf = *reinterpret_cast<const bf16x8*>(
                    Vt + (((size_t)(batch * 64 + n * 16 + c)) << 11) + key0 + st * 32 + g * 8);
                O[n] = MFMA16(pf, vf, O[n]);
            }
        }
    }

    // ---- write partials ----
    float* op = Opart + ((size_t)(qb * MAXCH + cid) * 16) * 64;
#pragma unroll
    for (int n = 0; n < 4; ++n)
#pragma unroll
        for (int i = 0; i < 4; ++i)
            op[(size_t)(g * 4 + i) * 64 + n * 16 + c] = O[n][i];
    if (c == 0) {
#pragma unroll
        for (int i = 0; i < 4; ++i)
            mlpart[(size_t)(qb * MAXCH + cid) * 16 + g * 4 + i] =
                make_float2(mx[i], rs[i]);
    }
}

// ---------------------------------------------------------------------------
// combine: grid = 512, block = 256 (4 waves; wave w handles rows w*4..w*4+3).
// ---------------------------------------------------------------------------
__global__ __launch_bounds__(256) void attn_combine_kernel(
    const float* __restrict__ Opart, const float2* __restrict__ mlpart,
    float* __restrict__ out)
{
    const int qb = blockIdx.x;
    const int d  = threadIdx.x & 63;
    const int w  = threadIdx.x >> 6;
    const int qbase = (qb * 16) & (SEQ - 1);
    const int NC = (qbase >> 6) / CT + 1;

#pragma unroll
    for (int ri = 0; ri < 4; ++ri) {
        const int r = w * 4 + ri;
        float m = -__builtin_inff();
        for (int ci = 0; ci < NC; ++ci)
            m = fmaxf(m, mlpart[(size_t)(qb * MAXCH + ci) * 16 + r].x);
        float l = 0.f, o = 0.f;
        for (int ci = 0; ci < NC; ++ci) {
            const float2 ml = mlpart[(size_t)(qb * MAXCH + ci) * 16 + r];
            const float wgt = __expf(ml.x - m);
            l += wgt * ml.y;
            o += wgt * Opart[((size_t)(qb * MAXCH + ci) * 16 + r) * 64 + d];
        }
        out[(size_t)(qb * 16 + r) * HD + d] = o / l;
    }
}

// ---------------------------------------------------------------------------
extern "C" void kernel_launch(void* const* d_in, const int* in_sizes, int n_in,
                              void* d_out, int out_size, void* d_ws, size_t ws_size,
                              hipStream_t stream)
{
    (void)in_sizes; (void)n_in; (void)out_size; (void)ws_size;
    const float* x  = (const float*)d_in[0];
    const float* Wq = (const float*)d_in[1];
    const float* bq = (const float*)d_in[2];
    const float* Wk = (const float*)d_in[3];
    const float* bk = (const float*)d_in[4];
    const float* Wv = (const float*)d_in[5];
    const float* bv = (const float*)d_in[6];
    float* out = (float*)d_out;

    char* ws = (char*)d_ws;
    short*  Qs     = (short*)(ws);                  // 1 MB
    short*  Kb     = (short*)(ws + (1u << 20));     // 1 MB
    short*  Vt     = (short*)(ws + (2u << 20));     // 1 MB  [4][64][2048]
    short*  wfrag  = (short*)(ws + (3u << 20));     // 384 KB
    float*  Opart  = (float*)(ws + (4u << 20));     // 16 MB
    float2* mlpart = (float2*)(ws + (20u << 20));   // 512 KB

    wprep_kernel<<<96, 256, 0, stream>>>(Wq, Wk, Wv, wfrag);
    proj_kernel<<<512, 256, 0, stream>>>(x, wfrag, bq, bk, bv, Qs, Kb, Vt);
    attn_kernel<<<576, 256, 0, stream>>>(Qs, Kb, Vt, Opart, mlpart);
    attn_combine_kernel<<<512, 256, 0, stream>>>(Opart, mlpart, out);
}